// Round 3
// baseline (1028.752 us; speedup 1.0000x reference)
//
#include <hip/hip_runtime.h>

// ---------------------------------------------------------------------------
// PerTokenFN: out[b,t,:] = GELU(x[b,t,:] @ W1[t] + b1[t]) @ W2[t] + b2[t]
// B=4096, T=64, D=256, H=1024.  fp32 in/out, bf16 MFMA compute.
//
// Round-4 build:
//  * prepasses (now LDS-tiled + coalesced: 512B/1KB row reads, ~16x less
//    overfetch than round-2) convert W1/W2 fp32 -> bf16 swizzled images in
//    d_ws, identical layout to round-2 (verified algebraically).
//  * main kernel reads weight FRAGMENTS directly from the global images
//    (each wave's fragment set is a permuted-contiguous 1-4KB slab ->
//    perfectly coalesced dwordx4, L2-resident per XCD). No weight LDS, no
//    staging barriers, no manual vmcnt: register double-buffer with real
//    data deps, compiler inserts counted vmcnt.
//  * x converted once per block into a swizzled 32KB LDS tile (frees the
//    64-VGPR xfrag -> occupancy 2->3 waves/SIMD via __launch_bounds__(256,3)).
//  * 2 fenced raw barriers per chunk (h-image visibility / reuse) instead of
//    24; lgkmcnt(0)-only before barriers so global prefetch stays in flight.
//  * falls back to the round-0 verified kernel if ws_size < 64 MB.
// ---------------------------------------------------------------------------

typedef __bf16 bf16x8 __attribute__((ext_vector_type(8)));
typedef float  floatx4 __attribute__((ext_vector_type(4)));

__device__ __forceinline__ unsigned short f2bf(float f) {
  unsigned u = __builtin_bit_cast(unsigned, f);
  u += 0x7fffu + ((u >> 16) & 1u);   // RNE
  return (unsigned short)(u >> 16);
}

__device__ __forceinline__ float gelu_exact(float v) {
  return 0.5f * v * (1.0f + erff(v * 0.70710678118654752f));
}

// ---------------------------------------------------------------------------
// Image layouts (byte offsets inside one K-step image) — same as round-2:
//  W1 image (8 KB, per (t,c,kk)):  elem(jl in[0,128), dl=q*8+i) at
//      jl*64 + (q ^ ((jl>>1)&3))*16 + i*2,   d = kk*32+dl, h = c*128+jl
//      image base byte = t*524288 + c*65536 + kk*8192
//  W2 image (16 KB, per (t,c,kk2)): elem(d in[0,256), jl32=q*8+i) at
//      d*64 + (q ^ ((d>>1)&3))*16 + i*2,     j = c*128+kk2*32+jl32
//      image base byte = t*524288 + c*65536 + kk2*16384
// ---------------------------------------------------------------------------

// W1 fp32 [t][d=256][h=1024] -> bf16 images. One block per (t,kk).
__global__ __launch_bounds__(256) void prep_w1(const float* __restrict__ w1,
                                               unsigned short* __restrict__ img) {
  __shared__ unsigned short simg[4096];  // one 8KB image
  const int u = threadIdx.x, bid = blockIdx.x;
  const int t = bid >> 3, kk = bid & 7;
  const float* base = w1 + (size_t)t * 262144 + (size_t)(kk * 32) * 1024;
  unsigned short* obase = img + (size_t)t * 262144 + kk * 4096;  // shorts

  for (int c = 0; c < 8; ++c) {
#pragma unroll
    for (int s = 0; s < 4; ++s) {
      const int i = (s * 256 + u) * 4;     // [0,4096)
      const int dl = i >> 7, col = i & 127;
      floatx4 f = *(const floatx4*)(base + (size_t)dl * 1024 + c * 128 + col);
      const int q = dl >> 3, i8 = dl & 7;
#pragma unroll
      for (int e = 0; e < 4; ++e) {
        const int jl = col + e;
        simg[jl * 32 + ((q ^ ((jl >> 1) & 3)) << 3) + i8] = f2bf(f[e]);
      }
    }
    __syncthreads();
    *(uint4*)(obase + (size_t)c * 32768 + u * 8) = *(const uint4*)(simg + u * 8);
    *(uint4*)(obase + (size_t)c * 32768 + 2048 + u * 8) =
        *(const uint4*)(simg + 2048 + u * 8);
    __syncthreads();
  }
}

// W2 fp32 [t][h=1024][d=256] -> bf16 images. One block per (t,c).
__global__ __launch_bounds__(256) void prep_w2(const float* __restrict__ w2,
                                               unsigned short* __restrict__ img) {
  __shared__ unsigned short simg[8192];  // one 16KB image
  const int u = threadIdx.x, bid = blockIdx.x;
  const int t = bid >> 3, c = bid & 7;
  const float* base = w2 + (size_t)t * 262144 + (size_t)(c * 128) * 256;
  unsigned short* obase = img + (size_t)t * 262144 + c * 32768;  // shorts

  for (int kk2 = 0; kk2 < 4; ++kk2) {
#pragma unroll
    for (int s = 0; s < 8; ++s) {
      const int i = (s * 256 + u) * 4;     // [0,8192)
      const int jr = i >> 8, d = i & 255;
      floatx4 f = *(const floatx4*)(base + (size_t)(kk2 * 32 + jr) * 256 + d);
      const int q = jr >> 3, i8 = jr & 7;
#pragma unroll
      for (int e = 0; e < 4; ++e) {
        const int dd = d + e;
        simg[dd * 32 + ((q ^ ((dd >> 1) & 3)) << 3) + i8] = f2bf(f[e]);
      }
    }
    __syncthreads();
#pragma unroll
    for (int r = 0; r < 4; ++r)
      *(uint4*)(obase + (size_t)kk2 * 8192 + (r * 256 + u) * 8) =
          *(const uint4*)(simg + (r * 256 + u) * 8);
    __syncthreads();
  }
}

// ---------------------------------------------------------------------------
// Main kernel.
// ---------------------------------------------------------------------------
__global__ __launch_bounds__(256, 3) void mlp_fast2(
    const float* __restrict__ x, const unsigned short* __restrict__ w1i,
    const float* __restrict__ b1, const unsigned short* __restrict__ w2i,
    const float* __restrict__ b2, float* __restrict__ out) {

  __shared__ __attribute__((aligned(16))) unsigned char lds[53248];
  unsigned char* const xlds = lds;              // 32KB: [k(8)][bl(64)] swz
  unsigned char* const hlds = lds + 32768;      // 16KB h image
  float* const b1lds = (float*)(lds + 49152);   // 4KB

  const int tid  = threadIdx.x;
  const int lane = tid & 63;
  const int w    = tid >> 6, wm = w >> 1, wn = w & 1;
  const int l15  = lane & 15, l4 = lane >> 4;

  const int bid = blockIdx.x;
  const int t   = (bid & 7) + 8 * (bid >> 9);   // t pinned per XCD
  const int b0  = ((bid >> 3) & 63) << 6;

  const unsigned char* w1t = (const unsigned char*)(w1i + (size_t)t * 262144);
  const unsigned char* w2t = (const unsigned char*)(w2i + (size_t)t * 262144);

  // ---- b1 -> LDS ----
#pragma unroll
  for (int i = 0; i < 4; ++i)
    b1lds[tid + 256 * i] = b1[t * 1024 + tid + 256 * i];

  // ---- x -> xlds (bf16, swizzled): elem(bl,d) at k*4096 + bl*64 +
  //      ((slot^(bl&3))<<4) + (d&7)*2, k=d>>5, slot=(d>>3)&3 ----
  {
    const int bl = tid >> 2, seg = tid & 3;
    const float* xr = x + ((size_t)(b0 + bl) * 64 + t) * 256 + seg * 64;
#pragma unroll
    for (int g = 0; g < 8; ++g) {
      const int d = seg * 64 + g * 8;
      floatx4 lo = *(const floatx4*)(xr + g * 8);
      floatx4 hi = *(const floatx4*)(xr + g * 8 + 4);
      union { uint4 v; unsigned short s[8]; } px;
      px.s[0] = f2bf(lo[0]); px.s[1] = f2bf(lo[1]);
      px.s[2] = f2bf(lo[2]); px.s[3] = f2bf(lo[3]);
      px.s[4] = f2bf(hi[0]); px.s[5] = f2bf(hi[1]);
      px.s[6] = f2bf(hi[2]); px.s[7] = f2bf(hi[3]);
      const int k = d >> 5, slot = (d >> 3) & 3;
      *(uint4*)(xlds + k * 4096 + bl * 64 + ((slot ^ (bl & 3)) << 4)) = px.v;
    }
  }

  // ---- out^T accumulators, init with b2 ----
  floatx4 oacc[4][4];
#pragma unroll
  for (int mt = 0; mt < 4; ++mt) {
    const floatx4 bv = *(const floatx4*)(b2 + t * 256 + w * 64 + mt * 16 + l4 * 4);
#pragma unroll
    for (int nt = 0; nt < 4; ++nt) oacc[mt][nt] = bv;
  }

  __syncthreads();   // xlds + b1lds visible

  const int swf    = (l4 ^ ((lane >> 1) & 3)) << 4;
  const int w1base = ((wn * 64 + l15) << 6) + swf;  // + nt*1024
  const int w2base = ((w * 64 + l15) << 6) + swf;   // + mt*1024
  const int xbase  = (wm * 32 + l15) * 64 + ((l4 ^ (l15 & 3)) << 4);  // + mt*1024

  // prologue: W1 fragments for flat step s=0
  bf16x8 bcur[4];
#pragma unroll
  for (int nt = 0; nt < 4; ++nt)
    bcur[nt] = *(const bf16x8*)(w1t + w1base + nt * 1024);

#pragma unroll 1
  for (int c = 0; c < 8; ++c) {
    // h accumulators, init b1
    floatx4 hacc[2][4];
#pragma unroll
    for (int nt = 0; nt < 4; ++nt) {
      const float bv = b1lds[c * 128 + wn * 64 + nt * 16 + l15];
      const floatx4 bb = {bv, bv, bv, bv};
      hacc[0][nt] = bb; hacc[1][nt] = bb;
    }

    // ------- GEMM1: 8 K-steps, reg-pipelined W1 frags, no barriers -------
#pragma unroll
    for (int k = 0; k < 8; ++k) {
      const int s = c * 8 + k;
      const unsigned char* nsrc =
          w1t + (size_t)((s < 63 ? s + 1 : 63) * 8192);
      bf16x8 bnxt[4];
#pragma unroll
      for (int nt = 0; nt < 4; ++nt)
        bnxt[nt] = *(const bf16x8*)(nsrc + w1base + nt * 1024);
      const bf16x8 xf0 = *(const bf16x8*)(xlds + k * 4096 + xbase);
      const bf16x8 xf1 = *(const bf16x8*)(xlds + k * 4096 + xbase + 1024);
      __builtin_amdgcn_s_setprio(1);
#pragma unroll
      for (int nt = 0; nt < 4; ++nt) {
        hacc[0][nt] = __builtin_amdgcn_mfma_f32_16x16x32_bf16(
            xf0, bcur[nt], hacc[0][nt], 0, 0, 0);
        hacc[1][nt] = __builtin_amdgcn_mfma_f32_16x16x32_bf16(
            xf1, bcur[nt], hacc[1][nt], 0, 0, 0);
      }
      __builtin_amdgcn_s_setprio(0);
#pragma unroll
      for (int nt = 0; nt < 4; ++nt) bcur[nt] = bnxt[nt];
    }

    // ------- GELU + h -> LDS (swizzled [b][j] image) -------
#pragma unroll
    for (int mt = 0; mt < 2; ++mt)
#pragma unroll
      for (int nt = 0; nt < 4; ++nt) {
        const int jl = wn * 64 + nt * 16 + l15;
        const int q  = jl >> 3;
        const int jo = (jl & 7) * 2;
#pragma unroll
        for (int r = 0; r < 4; ++r) {
          const float g = gelu_exact(hacc[mt][nt][r]);
          const int b = wm * 32 + mt * 16 + l4 * 4 + r;
          *(unsigned short*)(hlds + b * 256 + ((q ^ (b & 7)) * 16) + jo) = f2bf(g);
        }
      }

    // prefetch W2 fragments for k2=0 (global: survives the barrier)
    bf16x8 acur[4];
    {
      const unsigned char* asrc = w2t + (size_t)(c * 4) * 16384;
#pragma unroll
      for (int mt = 0; mt < 4; ++mt)
        acur[mt] = *(const bf16x8*)(asrc + w2base + mt * 1024);
    }

    asm volatile("s_waitcnt lgkmcnt(0)" ::: "memory");  // h writes drained
    __builtin_amdgcn_s_barrier();
    asm volatile("" ::: "memory");

    // ------- GEMM2: 4 K-steps, reg-pipelined W2 frags -------
#pragma unroll
    for (int k2 = 0; k2 < 4; ++k2) {
      bf16x8 anxt[4];
      if (k2 < 3) {
        const unsigned char* nsrc2 = w2t + (size_t)(c * 4 + k2 + 1) * 16384;
#pragma unroll
        for (int mt = 0; mt < 4; ++mt)
          anxt[mt] = *(const bf16x8*)(nsrc2 + w2base + mt * 1024);
      }
      bf16x8 hfr[4];
#pragma unroll
      for (int nt = 0; nt < 4; ++nt)
        hfr[nt] = *(const bf16x8*)(hlds + (nt * 16 + l15) * 256 +
                                   (((k2 * 4 + l4) ^ (lane & 7)) * 16));
      __builtin_amdgcn_s_setprio(1);
#pragma unroll
      for (int mt = 0; mt < 4; ++mt)
#pragma unroll
        for (int nt = 0; nt < 4; ++nt)
          oacc[mt][nt] = __builtin_amdgcn_mfma_f32_16x16x32_bf16(
              acur[mt], hfr[nt], oacc[mt][nt], 0, 0, 0);
      __builtin_amdgcn_s_setprio(0);
      if (k2 < 3) {
#pragma unroll
        for (int mt = 0; mt < 4; ++mt) acur[mt] = anxt[mt];
      }
    }

    asm volatile("s_waitcnt lgkmcnt(0)" ::: "memory");
    __builtin_amdgcn_s_barrier();   // h readers done -> next c may overwrite
    asm volatile("" ::: "memory");
  }

  // ---- epilogue: out^T regs -> out[b][t][d] ----
#pragma unroll
  for (int mt = 0; mt < 4; ++mt) {
    const int d = w * 64 + mt * 16 + l4 * 4;
#pragma unroll
    for (int nt = 0; nt < 4; ++nt) {
      const int b = b0 + nt * 16 + l15;
      *(floatx4*)(out + ((size_t)b * 64 + t) * 256 + d) = oacc[mt][nt];
    }
  }
}

// ---------------------------------------------------------------------------
// Round-0 verified kernel, kept verbatim as fallback if ws_size < 64 MB.
// ---------------------------------------------------------------------------
__global__ __launch_bounds__(256, 2) void mlp_kernel(
    const float* __restrict__ x, const float* __restrict__ w1,
    const float* __restrict__ b1, const float* __restrict__ w2,
    const float* __restrict__ b2, float* __restrict__ out) {

  __shared__ __attribute__((aligned(16))) unsigned char lds[40960];
  unsigned char* const w1img = lds;
  unsigned char* const w2img = lds + 8192;
  unsigned char* const hlds  = lds + 24576;

  const int tid  = threadIdx.x;
  const int lane = tid & 63;
  const int w    = tid >> 6;
  const int wm   = w >> 1;
  const int wn   = w & 1;
  const int l15  = lane & 15;
  const int l4   = lane >> 4;

  const int bid  = blockIdx.x;
  const int t    = (bid & 7) + 8 * (bid >> 9);
  const int b0   = ((bid >> 3) & 63) << 6;

  const float* w1t = w1 + (size_t)t * 262144;
  const float* w2t = w2 + (size_t)t * 262144;

  const int jl_s   = tid & 127;
  const int half_s = tid >> 7;
  const int P_s    = half_s ^ ((jl_s >> 2) & 1);
  const int sw2s   = (tid >> 1) & 3;

  bf16x8 xfrag[2][8];
#pragma unroll
  for (int mt = 0; mt < 2; ++mt) {
    const int b = b0 + wm * 32 + mt * 16 + l15;
    const float* xb = x + ((size_t)b * 64 + t) * 256 + l4 * 8;
#pragma unroll
    for (int kk = 0; kk < 8; ++kk) {
      floatx4 lo = *(const floatx4*)(xb + kk * 32);
      floatx4 hi = *(const floatx4*)(xb + kk * 32 + 4);
      union { bf16x8 v; unsigned short s[8]; } px;
      px.s[0] = f2bf(lo[0]); px.s[1] = f2bf(lo[1]);
      px.s[2] = f2bf(lo[2]); px.s[3] = f2bf(lo[3]);
      px.s[4] = f2bf(hi[0]); px.s[5] = f2bf(hi[1]);
      px.s[6] = f2bf(hi[2]); px.s[7] = f2bf(hi[3]);
      xfrag[mt][kk] = px.v;
    }
  }

  floatx4 oacc[4][4];
#pragma unroll
  for (int mt = 0; mt < 4; ++mt) {
    const floatx4 bv = *(const floatx4*)(b2 + t * 256 + w * 64 + mt * 16 + l4 * 4);
#pragma unroll
    for (int nt = 0; nt < 4; ++nt) oacc[mt][nt] = bv;
  }

  const int swf    = (l4 ^ ((lane >> 1) & 3)) << 4;
  const int w1base = ((wn * 64 + l15) << 6) + swf;
  const int w2base = ((w * 64 + l15) << 6) + swf;

#pragma unroll 1
  for (int c = 0; c < 8; ++c) {
    floatx4 hacc[2][4];
#pragma unroll
    for (int nt = 0; nt < 4; ++nt) {
      const float bv = b1[t * 1024 + c * 128 + wn * 64 + nt * 16 + l15];
      const floatx4 bb = {bv, bv, bv, bv};
      hacc[0][nt] = bb; hacc[1][nt] = bb;
    }

#pragma unroll
    for (int kk = 0; kk < 8; ++kk) {
      float f[16];
      const float* src = w1t + (size_t)(kk * 32 + half_s * 16) * 1024 + c * 128 + jl_s;
#pragma unroll
      for (int u = 0; u < 16; ++u) f[u] = src[(size_t)u * 1024];

      __syncthreads();
      union { uint4 v; unsigned short s[8]; } pk[2];
#pragma unroll
      for (int u = 0; u < 16; ++u) pk[u >> 3].s[u & 7] = f2bf(f[u]);
#pragma unroll
      for (int p = 0; p < 2; ++p) {
        const int m = 2 * P_s + p;
        const int s = (p ^ (jl_s >> 1)) & 1;
        *(uint4*)(w1img + jl_s * 64 + m * 16) = pk[s].v;
      }
      __syncthreads();

      bf16x8 bfrag[4];
#pragma unroll
      for (int nt = 0; nt < 4; ++nt)
        bfrag[nt] = *(const bf16x8*)(w1img + w1base + nt * 1024);
#pragma unroll
      for (int mt = 0; mt < 2; ++mt)
#pragma unroll
        for (int nt = 0; nt < 4; ++nt)
          hacc[mt][nt] = __builtin_amdgcn_mfma_f32_16x16x32_bf16(
              xfrag[mt][kk], bfrag[nt], hacc[mt][nt], 0, 0, 0);
    }

#pragma unroll
    for (int mt = 0; mt < 2; ++mt) {
#pragma unroll
      for (int nt = 0; nt < 4; ++nt) {
        const int jl = wn * 64 + nt * 16 + l15;
        const int q  = jl >> 3;
        const int jo = (jl & 7) * 2;
#pragma unroll
        for (int r = 0; r < 4; ++r) {
          const float g = gelu_exact(hacc[mt][nt][r]);
          const int b = wm * 32 + mt * 16 + l4 * 4 + r;
          *(unsigned short*)(hlds + b * 256 + ((q ^ (b & 7)) * 16) + jo) = f2bf(g);
        }
      }
    }

#pragma unroll
    for (int kk2 = 0; kk2 < 4; ++kk2) {
      float g2[32];
      const float* src2 = w2t + (size_t)(c * 128 + kk2 * 32) * 256 + tid;
#pragma unroll
      for (int v = 0; v < 32; ++v) g2[v] = src2[(size_t)v * 256];

      __syncthreads();
      union { uint4 v; unsigned short s[8]; } pk2[4];
#pragma unroll
      for (int v = 0; v < 32; ++v) pk2[v >> 3].s[v & 7] = f2bf(g2[v]);
#pragma unroll
      for (int p = 0; p < 4; ++p) {
        const int m = (p + (tid >> 1)) & 3;
        const int q = m ^ sw2s;
        *(uint4*)(w2img + tid * 64 + m * 16) = pk2[q].v;
      }
      __syncthreads();

      bf16x8 afrag[4];
#pragma unroll
      for (int mt = 0; mt < 4; ++mt)
        afrag[mt] = *(const bf16x8*)(w2img + w2base + mt * 1024);
      bf16x8 hfrag[4];
#pragma unroll
      for (int nt = 0; nt < 4; ++nt)
        hfrag[nt] = *(const bf16x8*)(hlds + (nt * 16 + l15) * 256 +
                                     (((kk2 * 4 + l4) ^ (lane & 7)) * 16));
#pragma unroll
      for (int mt = 0; mt < 4; ++mt)
#pragma unroll
        for (int nt = 0; nt < 4; ++nt)
          oacc[mt][nt] = __builtin_amdgcn_mfma_f32_16x16x32_bf16(
              afrag[mt], hfrag[nt], oacc[mt][nt], 0, 0, 0);
    }
  }

#pragma unroll
  for (int mt = 0; mt < 4; ++mt) {
    const int d = w * 64 + mt * 16 + l4 * 4;
#pragma unroll
    for (int nt = 0; nt < 4; ++nt) {
      const int b = b0 + nt * 16 + l15;
      *(floatx4*)(out + ((size_t)b * 64 + t) * 256 + d) = oacc[mt][nt];
    }
  }
}

// ---------------------------------------------------------------------------
extern "C" void kernel_launch(void* const* d_in, const int* in_sizes, int n_in,
                              void* d_out, int out_size, void* d_ws, size_t ws_size,
                              hipStream_t stream) {
  const float* x  = (const float*)d_in[0];
  const float* W1 = (const float*)d_in[1];
  const float* b1 = (const float*)d_in[2];
  const float* W2 = (const float*)d_in[3];
  const float* b2 = (const float*)d_in[4];
  float* out = (float*)d_out;

  const size_t need = 67108864;  // 32 MB W1 images + 32 MB W2 images
  if (d_ws != nullptr && ws_size >= need) {
    unsigned short* w1img = (unsigned short*)d_ws;
    unsigned short* w2img = (unsigned short*)((char*)d_ws + 33554432);
    prep_w1<<<512, 256, 0, stream>>>(W1, w1img);
    prep_w2<<<512, 256, 0, stream>>>(W2, w2img);
    mlp_fast2<<<4096, 256, 0, stream>>>(x, w1img, b1, w2img, b2, out);
  } else {
    mlp_kernel<<<4096, 256, 0, stream>>>(x, W1, b1, W2, b2, out);
  }
}